// Round 1
// baseline (8503.247 us; speedup 1.0000x reference)
//
#include <hip/hip_runtime.h>
#include <math.h>

#define Bsz 16384
#define Msz 512
#define Nsz 2048

// t[b] = (gamma/sqrt(M)) * ||v[b,:]||_2   (M = 512, one wave per row)
__global__ __launch_bounds__(256) void vnorm_kernel(const float* __restrict__ v,
                                                    float* __restrict__ t,
                                                    const float* __restrict__ gamma_p) {
    const int wave = threadIdx.x >> 6;
    const int lane = threadIdx.x & 63;
    const int b = (blockIdx.x << 2) + wave;
    const float* row = v + (size_t)b * Msz;
    float4 a = *(const float4*)(row + lane * 8);
    float4 c = *(const float4*)(row + lane * 8 + 4);
    float s = a.x*a.x + a.y*a.y + a.z*a.z + a.w*a.w
            + c.x*c.x + c.y*c.y + c.z*c.z + c.w*c.w;
#pragma unroll
    for (int off = 32; off > 0; off >>= 1) s += __shfl_down(s, off);
    if (lane == 0) t[b] = gamma_p[0] * 0.044194173824159216f * sqrtf(s);  // 1/sqrt(512)
}

// na[b] = ||alpha[b,:]||_2   (N = 2048, one wave per row)
__global__ __launch_bounds__(256) void anorm_kernel(const float* __restrict__ alpha,
                                                    float* __restrict__ na) {
    const int wave = threadIdx.x >> 6;
    const int lane = threadIdx.x & 63;
    const int b = (blockIdx.x << 2) + wave;
    const float* row = alpha + (size_t)b * Nsz;
    float s = 0.f;
#pragma unroll
    for (int i = 0; i < 8; ++i) {
        float4 a = *(const float4*)(row + (lane << 2) + (i << 8));
        s += a.x*a.x + a.y*a.y + a.z*a.z + a.w*a.w;
    }
#pragma unroll
    for (int off = 32; off > 0; off >>= 1) s += __shfl_down(s, off);
    if (lane == 0) na[b] = sqrtf(s);
}

// alpha[b,n] = relu( (first ? 0 : alpha[b,n]) + beta * dot(v[b,:], D[:,n]) - t[b] )
// 64x64 tile, 256 threads (16x16), 4x4 micro-tile, K = M = 512 in chunks of 16.
__global__ __launch_bounds__(256) void gemm1_kernel(const float* __restrict__ v,
                                                    const float* __restrict__ D,
                                                    const float* __restrict__ t,
                                                    float* __restrict__ alpha,
                                                    const float* __restrict__ beta_p,
                                                    int first) {
    __shared__ float Ast[16][68];   // [k][row], pad 68 -> 2-way banks (free)
    __shared__ float Bs[16][64];    // [k][n]
    const int tid = threadIdx.x;
    const int tx = tid & 15;
    const int ty = tid >> 4;
    const int b0 = blockIdx.y << 6;
    const int n0 = blockIdx.x << 6;

    float acc[4][4] = {};
    const int lrow = tid >> 2;          // 0..63 (A staging row)
    const int lk4  = (tid & 3) << 2;    // 0,4,8,12
    const int lkb  = tid >> 4;          // 0..15 (B staging k)
    const int lnb  = (tid & 15) << 2;   // 0..60

    const float* vrow = v + (size_t)(b0 + lrow) * Msz + lk4;
    const float* Drow = D + (size_t)lkb * Nsz + n0 + lnb;

    for (int k0 = 0; k0 < Msz; k0 += 16) {
        float4 av = *(const float4*)(vrow + k0);
        float4 bv = *(const float4*)(Drow + (size_t)k0 * Nsz);
        __syncthreads();
        Ast[lk4 + 0][lrow] = av.x;
        Ast[lk4 + 1][lrow] = av.y;
        Ast[lk4 + 2][lrow] = av.z;
        Ast[lk4 + 3][lrow] = av.w;
        *(float4*)&Bs[lkb][lnb] = bv;
        __syncthreads();
#pragma unroll
        for (int kk = 0; kk < 16; ++kk) {
            float4 a4 = *(const float4*)&Ast[kk][ty << 2];
            float4 b4 = *(const float4*)&Bs[kk][tx << 2];
            float a[4] = {a4.x, a4.y, a4.z, a4.w};
            float bb[4] = {b4.x, b4.y, b4.z, b4.w};
#pragma unroll
            for (int i = 0; i < 4; ++i)
#pragma unroll
                for (int j = 0; j < 4; ++j)
                    acc[i][j] = fmaf(a[i], bb[j], acc[i][j]);
        }
    }

    const float beta = beta_p[0];
#pragma unroll
    for (int i = 0; i < 4; ++i) {
        const int b = b0 + (ty << 2) + i;
        const float tb = t[b];
        float* arow = alpha + (size_t)b * Nsz + n0 + (tx << 2);
        float4 zold;
        if (first) zold = make_float4(0.f, 0.f, 0.f, 0.f);
        else       zold = *(const float4*)arow;
        float4 o;
        o.x = fmaxf(fmaf(beta, acc[i][0], zold.x) - tb, 0.f);
        o.y = fmaxf(fmaf(beta, acc[i][1], zold.y) - tb, 0.f);
        o.z = fmaxf(fmaf(beta, acc[i][2], zold.z) - tb, 0.f);
        o.w = fmaxf(fmaf(beta, acc[i][3], zold.w) - tb, 0.f);
        *(float4*)arow = o;
    }
}

// vout[b,m] = y[b,m] - beta * dot(alpha[b,:], D[m,:]) + (beta/512)*na[b]*vin[b,m]
// 64x64 tile, K = N = 2048 in chunks of 16.
__global__ __launch_bounds__(256) void gemm2_kernel(const float* __restrict__ alpha,
                                                    const float* __restrict__ D,
                                                    const float* __restrict__ y,
                                                    const float* __restrict__ na,
                                                    const float* __restrict__ vin,
                                                    float* __restrict__ vout,
                                                    const float* __restrict__ beta_p) {
    __shared__ float Ast[16][68];   // [k][b-row]
    __shared__ float Dt[16][68];    // [k][m-row]
    const int tid = threadIdx.x;
    const int tx = tid & 15;
    const int ty = tid >> 4;
    const int b0 = blockIdx.y << 6;
    const int m0 = blockIdx.x << 6;

    float acc[4][4] = {};
    const int lrow = tid >> 2;
    const int lk4  = (tid & 3) << 2;

    const float* arow = alpha + (size_t)(b0 + lrow) * Nsz + lk4;
    const float* drow = D + (size_t)(m0 + lrow) * Nsz + lk4;

    for (int k0 = 0; k0 < Nsz; k0 += 16) {
        float4 av = *(const float4*)(arow + k0);
        float4 dv = *(const float4*)(drow + k0);
        __syncthreads();
        Ast[lk4 + 0][lrow] = av.x;
        Ast[lk4 + 1][lrow] = av.y;
        Ast[lk4 + 2][lrow] = av.z;
        Ast[lk4 + 3][lrow] = av.w;
        Dt[lk4 + 0][lrow] = dv.x;
        Dt[lk4 + 1][lrow] = dv.y;
        Dt[lk4 + 2][lrow] = dv.z;
        Dt[lk4 + 3][lrow] = dv.w;
        __syncthreads();
#pragma unroll
        for (int kk = 0; kk < 16; ++kk) {
            float4 a4 = *(const float4*)&Ast[kk][ty << 2];
            float4 d4 = *(const float4*)&Dt[kk][tx << 2];
            float a[4] = {a4.x, a4.y, a4.z, a4.w};
            float dd[4] = {d4.x, d4.y, d4.z, d4.w};
#pragma unroll
            for (int i = 0; i < 4; ++i)
#pragma unroll
                for (int j = 0; j < 4; ++j)
                    acc[i][j] = fmaf(a[i], dd[j], acc[i][j]);
        }
    }

    const float beta = beta_p[0];
#pragma unroll
    for (int i = 0; i < 4; ++i) {
        const int b = b0 + (ty << 2) + i;
        const float cb = beta * (1.0f / 512.0f) * na[b];
        const size_t off = (size_t)b * Msz + m0 + (tx << 2);
        float4 yv = *(const float4*)(y + off);
        float4 vv = *(const float4*)(vin + off);
        float4 o;
        o.x = yv.x - beta * acc[i][0] + cb * vv.x;
        o.y = yv.y - beta * acc[i][1] + cb * vv.y;
        o.z = yv.z - beta * acc[i][2] + cb * vv.z;
        o.w = yv.w - beta * acc[i][3] + cb * vv.w;
        *(float4*)(vout + off) = o;
    }
}

extern "C" void kernel_launch(void* const* d_in, const int* in_sizes, int n_in,
                              void* d_out, int out_size, void* d_ws, size_t ws_size,
                              hipStream_t stream) {
    (void)in_sizes; (void)n_in; (void)out_size; (void)ws_size;
    const float* batch   = (const float*)d_in[0];   // [B, M]
    const float* D       = (const float*)d_in[1];   // [M, N]
    const float* gamma_p = (const float*)d_in[2];   // scalar
    const float* beta_p  = (const float*)d_in[3];   // scalar

    float* alpha = (float*)d_out;                   // [B, N], updated in place
    float* v_ws  = (float*)d_ws;                    // [B, M]
    float* t_ws  = v_ws + (size_t)Bsz * Msz;        // [B]
    float* na_ws = t_ws + Bsz;                      // [B]

    dim3 g1(Nsz / 64, Bsz / 64);   // (32, 256)
    dim3 g2(Msz / 64, Bsz / 64);   // (8, 256)

    for (int it = 0; it < 10; ++it) {
        const float* vcur = (it == 0) ? batch : v_ws;
        vnorm_kernel<<<Bsz / 4, 256, 0, stream>>>(vcur, t_ws, gamma_p);
        gemm1_kernel<<<g1, 256, 0, stream>>>(vcur, D, t_ws, alpha, beta_p, it == 0 ? 1 : 0);
        if (it < 9) {   // last iteration's new_v is unused by the reference output
            anorm_kernel<<<Bsz / 4, 256, 0, stream>>>(alpha, na_ws);
            gemm2_kernel<<<g2, 256, 0, stream>>>(alpha, D, batch, na_ws, vcur, v_ws, beta_p);
        }
    }
}

// Round 3
// 3083.043 us; speedup vs baseline: 2.7581x; 2.7581x over previous
//
#include <hip/hip_runtime.h>
#include <math.h>

#define Bsz 16384
#define Msz 512
#define Nsz 2048

typedef _Float16 half8 __attribute__((ext_vector_type(8)));
typedef _Float16 half4 __attribute__((ext_vector_type(4)));
typedef float floatx4 __attribute__((ext_vector_type(4)));

struct HL { _Float16 h, l; };
__device__ __forceinline__ HL split1(float x) {
    HL r;
    r.h = (_Float16)x;
    r.l = (_Float16)(x - (float)r.h);   // exact residual (two-term split)
    return r;
}

// t[b] = (gamma/sqrt(M)) * ||v[b,:]||_2   (M = 512, one wave per row)
__global__ __launch_bounds__(256) void vnorm_kernel(const float* __restrict__ v,
                                                    float* __restrict__ t,
                                                    const float* __restrict__ gamma_p) {
    const int wave = threadIdx.x >> 6;
    const int lane = threadIdx.x & 63;
    const int b = (blockIdx.x << 2) + wave;
    const float* row = v + (size_t)b * Msz;
    float4 a = *(const float4*)(row + lane * 8);
    float4 c = *(const float4*)(row + lane * 8 + 4);
    float s = a.x*a.x + a.y*a.y + a.z*a.z + a.w*a.w
            + c.x*c.x + c.y*c.y + c.z*c.z + c.w*c.w;
#pragma unroll
    for (int off = 32; off > 0; off >>= 1) s += __shfl_down(s, off);
    if (lane == 0) t[b] = gamma_p[0] * 0.044194173824159216f * sqrtf(s);  // 1/sqrt(512)
}

// na[b] = ||alpha[b,:]||_2   (N = 2048, one wave per row)
__global__ __launch_bounds__(256) void anorm_kernel(const float* __restrict__ alpha,
                                                    float* __restrict__ na) {
    const int wave = threadIdx.x >> 6;
    const int lane = threadIdx.x & 63;
    const int b = (blockIdx.x << 2) + wave;
    const float* row = alpha + (size_t)b * Nsz;
    float s = 0.f;
#pragma unroll
    for (int i = 0; i < 8; ++i) {
        float4 a = *(const float4*)(row + (lane << 2) + (i << 8));
        s += a.x*a.x + a.y*a.y + a.z*a.z + a.w*a.w;
    }
#pragma unroll
    for (int off = 32; off > 0; off >>= 1) s += __shfl_down(s, off);
    if (lane == 0) na[b] = sqrtf(s);
}

// One-time per launch: D [M][N] fp32 -> Dhi/Dlo [M][N] f16 (k=n contig, for gemm2 B)
//                               and Dthi/Dtlo [N][M] f16 (k=m contig, for gemm1 B)
__global__ __launch_bounds__(256) void convD_kernel(const float* __restrict__ D,
        _Float16* __restrict__ Dhi, _Float16* __restrict__ Dlo,
        _Float16* __restrict__ Dthi, _Float16* __restrict__ Dtlo) {
    __shared__ float T[64][65];
    const int t = threadIdx.x;
    const int tx = t & 15, ty = t >> 4;
    const int n0 = blockIdx.x << 6, m0 = blockIdx.y << 6;
#pragma unroll
    for (int q = 0; q < 4; ++q) {
        const int mr = (ty << 2) + q;
        const int nc = tx << 2;
        float4 d = *(const float4*)(D + (size_t)(m0 + mr) * Nsz + n0 + nc);
        half4 h, l;
        HL s0 = split1(d.x), s1 = split1(d.y), s2 = split1(d.z), s3 = split1(d.w);
        h[0] = s0.h; l[0] = s0.l; h[1] = s1.h; l[1] = s1.l;
        h[2] = s2.h; l[2] = s2.l; h[3] = s3.h; l[3] = s3.l;
        *(half4*)(Dhi + (size_t)(m0 + mr) * Nsz + n0 + nc) = h;
        *(half4*)(Dlo + (size_t)(m0 + mr) * Nsz + n0 + nc) = l;
        T[nc + 0][mr] = d.x; T[nc + 1][mr] = d.y;
        T[nc + 2][mr] = d.z; T[nc + 3][mr] = d.w;
    }
    __syncthreads();
#pragma unroll
    for (int q = 0; q < 4; ++q) {
        const int nr = (ty << 2) + q;
        const int mc = tx << 2;
        float4 d = make_float4(T[nr][mc], T[nr][mc + 1], T[nr][mc + 2], T[nr][mc + 3]);
        half4 h, l;
        HL s0 = split1(d.x), s1 = split1(d.y), s2 = split1(d.z), s3 = split1(d.w);
        h[0] = s0.h; l[0] = s0.l; h[1] = s1.h; l[1] = s1.l;
        h[2] = s2.h; l[2] = s2.l; h[3] = s3.h; l[3] = s3.l;
        *(half4*)(Dthi + (size_t)(n0 + nr) * Msz + m0 + mc) = h;
        *(half4*)(Dtlo + (size_t)(n0 + nr) * Msz + m0 + mc) = l;
    }
}

// C[128x128] tile GEMM with split-f16 3-term MFMA.
// A: fp32 [B][K] (k-contig), converted to hi/lo on the fly.
// B: pre-split f16 hi/lo arrays, row-major [outcol][K] (k-contig).
// MODE 0 (gemm1): out=alpha, epilogue relu(beta*acc + (first?0:alpha) - t[b]).
// MODE 1 (gemm2): out=v, epilogue y - beta*acc + (beta/512)*na[b]*vin.
template<int K, int MODE>
__global__ __launch_bounds__(256, 2) void gemm_split(
        const float* __restrict__ A,
        const _Float16* __restrict__ Bh,
        const _Float16* __restrict__ Bl,
        const float* __restrict__ scal,
        const float* __restrict__ y,
        const float* __restrict__ vin,
        float* __restrict__ out,
        const float* __restrict__ beta_p,
        int first) {
    constexpr int OS = (MODE == 0) ? Nsz : Msz;
    __shared__ _Float16 lds[4 * 128 * 40];   // Ahi, Alo, Bhi, Blo — rows padded to 40 f16 (80B)
    _Float16* Ah  = lds;
    _Float16* Al  = lds + 5120;
    _Float16* Bhs = lds + 10240;
    _Float16* Bls = lds + 15360;

    const int tid  = threadIdx.x;
    const int wave = tid >> 6, lane = tid & 63;
    const int wy = wave >> 1, wx = wave & 1;
    const int lm = lane & 15, lq = lane >> 4;
    const int b0 = blockIdx.y << 7;
    const int c0 = blockIdx.x << 7;

    floatx4 acc[4][4] = {};

    const int srow = tid >> 1;          // staging row 0..127
    const int skq  = (tid & 1) << 4;    // 0 or 16

    const float*    aP  = A  + (size_t)(b0 + srow) * K + skq;
    const _Float16* bhP = Bh + (size_t)(c0 + srow) * K + skq;
    const _Float16* blP = Bl + (size_t)(c0 + srow) * K + skq;

    _Float16* AhW = Ah  + srow * 40 + skq;
    _Float16* AlW = Al  + srow * 40 + skq;
    _Float16* BhW = Bhs + srow * 40 + skq;
    _Float16* BlW = Bls + srow * 40 + skq;

    const int aOff = (wy * 64 + lm) * 40 + lq * 8;
    const int bOff = (wx * 64 + lm) * 40 + lq * 8;

    for (int k0 = 0; k0 < K; k0 += 32) {
        float4 f0 = *(const float4*)(aP);
        float4 f1 = *(const float4*)(aP + 4);
        float4 f2 = *(const float4*)(aP + 8);
        float4 f3 = *(const float4*)(aP + 12);
        half8 gbh0 = *(const half8*)(bhP);
        half8 gbh1 = *(const half8*)(bhP + 8);
        half8 gbl0 = *(const half8*)(blP);
        half8 gbl1 = *(const half8*)(blP + 8);
        aP += 32; bhP += 32; blP += 32;

        half8 h0, h1, l0, l1;
        {
            HL s;
            s = split1(f0.x); h0[0] = s.h; l0[0] = s.l;
            s = split1(f0.y); h0[1] = s.h; l0[1] = s.l;
            s = split1(f0.z); h0[2] = s.h; l0[2] = s.l;
            s = split1(f0.w); h0[3] = s.h; l0[3] = s.l;
            s = split1(f1.x); h0[4] = s.h; l0[4] = s.l;
            s = split1(f1.y); h0[5] = s.h; l0[5] = s.l;
            s = split1(f1.z); h0[6] = s.h; l0[6] = s.l;
            s = split1(f1.w); h0[7] = s.h; l0[7] = s.l;
            s = split1(f2.x); h1[0] = s.h; l1[0] = s.l;
            s = split1(f2.y); h1[1] = s.h; l1[1] = s.l;
            s = split1(f2.z); h1[2] = s.h; l1[2] = s.l;
            s = split1(f2.w); h1[3] = s.h; l1[3] = s.l;
            s = split1(f3.x); h1[4] = s.h; l1[4] = s.l;
            s = split1(f3.y); h1[5] = s.h; l1[5] = s.l;
            s = split1(f3.z); h1[6] = s.h; l1[6] = s.l;
            s = split1(f3.w); h1[7] = s.h; l1[7] = s.l;
        }

        __syncthreads();
        *(half8*)AhW = h0;  *(half8*)(AhW + 8) = h1;
        *(half8*)AlW = l0;  *(half8*)(AlW + 8) = l1;
        *(half8*)BhW = gbh0; *(half8*)(BhW + 8) = gbh1;
        *(half8*)BlW = gbl0; *(half8*)(BlW + 8) = gbl1;
        __syncthreads();

        half8 fah[4], fal[4];
#pragma unroll
        for (int i = 0; i < 4; ++i) {
            fah[i] = *(const half8*)(Ah + aOff + i * 640);
            fal[i] = *(const half8*)(Al + aOff + i * 640);
        }
#pragma unroll
        for (int j = 0; j < 4; ++j) {
            half8 fbh = *(const half8*)(Bhs + bOff + j * 640);
            half8 fbl = *(const half8*)(Bls + bOff + j * 640);
#pragma unroll
            for (int i = 0; i < 4; ++i) {
                acc[i][j] = __builtin_amdgcn_mfma_f32_16x16x32_f16(fah[i], fbh, acc[i][j], 0, 0, 0);
                acc[i][j] = __builtin_amdgcn_mfma_f32_16x16x32_f16(fah[i], fbl, acc[i][j], 0, 0, 0);
                acc[i][j] = __builtin_amdgcn_mfma_f32_16x16x32_f16(fal[i], fbh, acc[i][j], 0, 0, 0);
            }
        }
    }

    const float beta = beta_p[0];
#pragma unroll
    for (int i = 0; i < 4; ++i) {
#pragma unroll
        for (int r = 0; r < 4; ++r) {
            const int b = b0 + wy * 64 + i * 16 + lq * 4 + r;
            if (MODE == 0) {
                const float tb = scal[b];
#pragma unroll
                for (int j = 0; j < 4; ++j) {
                    const size_t idx = (size_t)b * OS + c0 + wx * 64 + j * 16 + lm;
                    float z = first ? 0.f : out[idx];
                    out[idx] = fmaxf(fmaf(beta, acc[i][j][r], z) - tb, 0.f);
                }
            } else {
                const float cb = beta * (1.0f / 512.0f) * scal[b];
#pragma unroll
                for (int j = 0; j < 4; ++j) {
                    const size_t idx = (size_t)b * OS + c0 + wx * 64 + j * 16 + lm;
                    out[idx] = y[idx] - beta * acc[i][j][r] + cb * vin[idx];
                }
            }
        }
    }
}

extern "C" void kernel_launch(void* const* d_in, const int* in_sizes, int n_in,
                              void* d_out, int out_size, void* d_ws, size_t ws_size,
                              hipStream_t stream) {
    (void)in_sizes; (void)n_in; (void)out_size; (void)ws_size;
    const float* batch   = (const float*)d_in[0];   // [B, M]
    const float* D       = (const float*)d_in[1];   // [M, N]
    const float* gamma_p = (const float*)d_in[2];   // scalar
    const float* beta_p  = (const float*)d_in[3];   // scalar

    float* alpha = (float*)d_out;                   // [B, N], updated in place

    // workspace layout (~42 MB)
    float*     v_ws = (float*)d_ws;                                   // [B*M] fp32
    _Float16*  Dhi  = (_Float16*)((char*)d_ws + (size_t)Bsz * Msz * 4);
    _Float16*  Dlo  = Dhi  + (size_t)Msz * Nsz;
    _Float16*  Dthi = Dlo  + (size_t)Msz * Nsz;
    _Float16*  Dtlo = Dthi + (size_t)Msz * Nsz;
    float*     t_ws = (float*)(Dtlo + (size_t)Msz * Nsz);             // [B]
    float*     na_ws = t_ws + Bsz;                                    // [B]

    convD_kernel<<<dim3(Nsz / 64, Msz / 64), 256, 0, stream>>>(D, Dhi, Dlo, Dthi, Dtlo);

    dim3 g1(Nsz / 128, Bsz / 128);   // (16, 128)
    dim3 g2(Msz / 128, Bsz / 128);   // (4, 128)

    for (int it = 0; it < 10; ++it) {
        const float* vcur = (it == 0) ? batch : v_ws;
        vnorm_kernel<<<Bsz / 4, 256, 0, stream>>>(vcur, t_ws, gamma_p);
        gemm_split<Msz, 0><<<g1, 256, 0, stream>>>(vcur, Dthi, Dtlo, t_ws,
                                                   nullptr, nullptr, alpha, beta_p,
                                                   it == 0 ? 1 : 0);
        if (it < 9) {   // last iteration's new_v is unused by the reference output
            anorm_kernel<<<Bsz / 4, 256, 0, stream>>>(alpha, na_ws);
            gemm_split<Nsz, 1><<<g2, 256, 0, stream>>>(alpha, Dhi, Dlo, na_ws,
                                                       batch, vcur, v_ws, beta_p, 0);
        }
    }
}